// Round 4
// baseline (323.595 us; speedup 1.0000x reference)
//
#include <hip/hip_runtime.h>

#define B_ 256
#define T_ 256
#define C_ 384
#define H_ 384

typedef float f4 __attribute__((ext_vector_type(4)));
typedef float f32x4 __attribute__((ext_vector_type(4)));
typedef short bf8 __attribute__((ext_vector_type(8)));
typedef short s8v __attribute__((ext_vector_type(8)));
typedef short s4v __attribute__((ext_vector_type(4)));

__device__ __forceinline__ short f2bf(float f) {
  unsigned u = __builtin_bit_cast(unsigned, f);
  u += 0x7FFFu + ((u >> 16) & 1u);   // RNE; inputs are finite
  return (short)(u >> 16);
}

__device__ __forceinline__ void gload_lds16(const void* g, void* l) {
  __builtin_amdgcn_global_load_lds(
      (const __attribute__((address_space(1))) unsigned int*)g,
      (__attribute__((address_space(3))) unsigned int*)l, 16, 0, 0);
}

// ---------------------------------------------------------------------------
// Kernel 1: fp32 -> bf16 conversion for x and the three weight matrices.
// ---------------------------------------------------------------------------
__global__ __launch_bounds__(256) void convert_kernel(
    const float* __restrict__ x, const float* __restrict__ wk,
    const float* __restrict__ wq, const float* __restrict__ wv,
    short* __restrict__ xb, short* __restrict__ wb) {
  const int NXG = (B_ * T_ * C_) / 8;
  const int NWG = (H_ * C_) / 8;
  const int total = NXG + 3 * NWG;
  for (int g = blockIdx.x * 256 + threadIdx.x; g < total; g += gridDim.x * 256) {
    const float* src;
    short* dst;
    if (g < NXG) {
      src = x + (size_t)g * 8;
      dst = xb + (size_t)g * 8;
    } else {
      int h = g - NXG;
      int wsel = h / NWG;
      int o = h - wsel * NWG;
      const float* wp = wsel == 0 ? wk : (wsel == 1 ? wq : wv);
      src = wp + (size_t)o * 8;
      dst = wb + (size_t)wsel * (H_ * C_) + (size_t)o * 8;
    }
    f4 f0 = *(const f4*)src;
    f4 f1 = *(const f4*)(src + 4);
    s8v r;
    r[0] = f2bf(f0[0]); r[1] = f2bf(f0[1]); r[2] = f2bf(f0[2]); r[3] = f2bf(f0[3]);
    r[4] = f2bf(f1[0]); r[5] = f2bf(f1[1]); r[6] = f2bf(f1[2]); r[7] = f2bf(f1[3]);
    *(s8v*)dst = r;
  }
}

// ---------------------------------------------------------------------------
// Kernel 2: QKV projection GEMM.
// BM=512, BN=128, BK=64. 512 threads = 8 waves as 4M x 2N, each wave owns a
// 128x64 output tile (8 M-frags x 4 N-frags) -> 24 unique ds_read_b128 per
// 64 MFMA per K-step (1:2.67), vs 1:1 effective before (the LDS-read bound).
// Double-buffered LDS = 160 KiB exactly; counted vmcnt(10) keeps one stage
// in flight across raw barriers (T3+T4). T2 source-preswizzle; T1 XCD swizzle
// (grid 1152 = 8*144, bijective; 9 consecutive blocks share an A panel).
// ---------------------------------------------------------------------------
__global__ __launch_bounds__(512, 2) void proj_gemm(
    const short* __restrict__ xb, const short* __restrict__ wb,
    short* __restrict__ kb, short* __restrict__ qbuf, short* __restrict__ vt) {
  __shared__ __align__(16) short lA[2][512 * 64];   // 128 KiB
  __shared__ __align__(16) short lB[2][128 * 64];   //  32 KiB
  const int tid = threadIdx.x;
  const int bid = blockIdx.x;
  const int swz = (bid & 7) * 144 + (bid >> 3);
  const int nb = swz % 9;
  const int mb = swz / 9;
  const int m0 = mb * 512, gn0 = nb * 128;
  const int w = tid >> 6, l = tid & 63;
  const int wrm = w >> 1, wcn = w & 1;   // 4M x 2N wave grid

  // stage one K-tile (A: 512x64, B: 128x64) into buffer `buf` (10 loads/thread)
  auto STAGE = [&](int buf, int t) {
    const int k0 = t * 64;
#pragma unroll
    for (int j = 0; j < 8; ++j) {
      const int flat = j * 512 + tid;
      const int row = flat >> 3;
      const int colg = ((flat & 7) ^ (row & 7)) * 8;  // pre-swizzled source
      gload_lds16(xb + (size_t)(m0 + row) * C_ + k0 + colg,
                  (char*)&lA[buf][0] + flat * 16);
    }
#pragma unroll
    for (int j = 0; j < 2; ++j) {
      const int flat = j * 512 + tid;
      const int row = flat >> 3;
      const int colg = ((flat & 7) ^ (row & 7)) * 8;
      gload_lds16(wb + (size_t)(gn0 + row) * C_ + k0 + colg,
                  (char*)&lB[buf][0] + flat * 16);
    }
  };

  f32x4 acc[8][4] = {};
  STAGE(0, 0);
#pragma unroll
  for (int t = 0; t < 6; ++t) {
    const int cur = t & 1;
    if (t < 5) {
      STAGE(cur ^ 1, t + 1);                       // issue next tile early
      asm volatile("s_waitcnt vmcnt(10)" ::: "memory");  // wait oldest only
    } else {
      asm volatile("s_waitcnt vmcnt(0)" ::: "memory");
    }
    __builtin_amdgcn_s_barrier();                  // tile t fully in LDS
    __builtin_amdgcn_sched_barrier(0);
    const short* A = &lA[cur][0];
    const short* Bt = &lB[cur][0];
#pragma unroll
    for (int ks = 0; ks < 2; ++ks) {               // two K=32 slices
      const int kg = ks * 4 + (l >> 4);            // K-granule 0..7
      bf8 av[8], bv[4];
#pragma unroll
      for (int mt = 0; mt < 8; ++mt) {
        const int ra = wrm * 128 + mt * 16 + (l & 15);
        av[mt] = *(const bf8*)&A[ra * 64 + ((kg ^ (ra & 7)) << 3)];
      }
#pragma unroll
      for (int nt = 0; nt < 4; ++nt) {
        const int rb = wcn * 64 + nt * 16 + (l & 15);
        bv[nt] = *(const bf8*)&Bt[rb * 64 + ((kg ^ (rb & 7)) << 3)];
      }
      __builtin_amdgcn_s_setprio(1);
#pragma unroll
      for (int mt = 0; mt < 8; ++mt)
#pragma unroll
        for (int nt = 0; nt < 4; ++nt)
          acc[mt][nt] = __builtin_amdgcn_mfma_f32_16x16x32_bf16(
              av[mt], bv[nt], acc[mt][nt], 0, 0, 0);
      __builtin_amdgcn_s_setprio(0);
    }
    __builtin_amdgcn_sched_barrier(0);
    __builtin_amdgcn_s_barrier();                  // done reading buf[cur]
  }
  // epilogue: token = m0 + wrm*128 + mt*16 + (l>>4)*4 + r ; col = gcb + nt*16
  const int proj = nb / 3;
  const int gcb = (nb % 3) * 128 + wcn * 64 + (l & 15);
  const int tok0 = m0 + wrm * 128 + ((l >> 4) * 4);
  if (proj < 2) {
    short* dst = proj == 0 ? kb : qbuf;
#pragma unroll
    for (int mt = 0; mt < 8; ++mt)
#pragma unroll
      for (int nt = 0; nt < 4; ++nt)
#pragma unroll
        for (int r = 0; r < 4; ++r)
          dst[(size_t)(tok0 + mt * 16 + r) * H_ + gcb + nt * 16] =
              f2bf(acc[mt][nt][r]);
  } else {
    // vt[b][h][t]; the wave's 128 tokens never cross a 256-token batch
    const int bb = tok0 >> 8;
    const int tl0 = tok0 & 255;
#pragma unroll
    for (int mt = 0; mt < 8; ++mt)
#pragma unroll
      for (int nt = 0; nt < 4; ++nt) {
        s4v pk;
        pk[0] = f2bf(acc[mt][nt][0]); pk[1] = f2bf(acc[mt][nt][1]);
        pk[2] = f2bf(acc[mt][nt][2]); pk[3] = f2bf(acc[mt][nt][3]);
        *(s4v*)&vt[(size_t)bb * (H_ * T_) + (size_t)(gcb + nt * 16) * T_ +
                   tl0 + mt * 16] = pk;
      }
  }
}

// ---------------------------------------------------------------------------
// Kernel 3: causal attention (unchanged from round 3: XOR-swizzled LDS,
// XCD batch-grouping swizzle).
// ---------------------------------------------------------------------------
__global__ __launch_bounds__(256) void attn_kernel(
    const short* __restrict__ qbuf, const short* __restrict__ kb,
    const short* __restrict__ vt, float* __restrict__ out) {
  __shared__ __align__(16) char smem[40960];
  short* Kl = (short*)smem;
  short* Ql = (short*)(smem + 32768);
  short* Pl = (short*)smem;
  const int bid = blockIdx.x;
  const int swzb = (bid & 7) * 128 + (bid >> 3);
  const int b = swzb >> 2;
  const int qi = swzb & 3;
  const int t0 = qi * 64;
  const int SKV = t0 + 64;
  const int ntile = SKV >> 4;
  const int tid = threadIdx.x;
  const int w = tid >> 6, l = tid & 63;
  f32x4 sa[16] = {};
  for (int hc = 0; hc < 6; ++hc) {
    const int h0 = hc * 64;
#pragma unroll
    for (int j = 0; j < 2; ++j) {
      const int flat = j * 256 + tid;
      const int row = flat >> 3;
      const int colg = ((flat & 7) ^ (row & 7)) * 8;
      gload_lds16(qbuf + (size_t)(b * T_ + t0 + row) * H_ + h0 + colg,
                  (char*)Ql + flat * 16);
    }
    const int kiss = SKV >> 5;
    for (int j = 0; j < kiss; ++j) {
      const int flat = j * 256 + tid;
      const int row = flat >> 3;
      const int colg = ((flat & 7) ^ (row & 7)) * 8;
      gload_lds16(kb + (size_t)(b * T_ + row) * H_ + h0 + colg,
                  (char*)Kl + flat * 16);
    }
    __syncthreads();
#pragma unroll
    for (int ks = 0; ks < 2; ++ks) {
      const int kg = ks * 4 + (l >> 4);
      const int rq = w * 16 + (l & 15);
      bf8 av = *(const bf8*)&Ql[rq * 64 + ((kg ^ (rq & 7)) << 3)];
#pragma unroll
      for (int nt = 0; nt < 16; ++nt)
        if (nt < ntile) {
          const int rk = nt * 16 + (l & 15);
          bf8 bv = *(const bf8*)&Kl[rk * 64 + ((kg ^ (rk & 7)) << 3)];
          sa[nt] = __builtin_amdgcn_mfma_f32_16x16x32_bf16(av, bv, sa[nt], 0, 0, 0);
        }
    }
    __syncthreads();
  }
  const float scale = 0.05103103630798287f;  // 384^-0.5
  const int rbl = w * 16 + (l >> 4) * 4;
#pragma unroll
  for (int r = 0; r < 4; ++r) {
    const int prow = rbl + r;
    const int trow = t0 + prow;
    float vv[16];
    float m = -3.0e38f;
#pragma unroll
    for (int nt = 0; nt < 16; ++nt)
      if (nt < ntile) {
        const int col = nt * 16 + (l & 15);
        float v = sa[nt][r] * scale;
        if (col > trow) v = -3.0e38f;
        vv[nt] = v;
        m = fmaxf(m, v);
      }
    m = fmaxf(m, __shfl_xor(m, 1));
    m = fmaxf(m, __shfl_xor(m, 2));
    m = fmaxf(m, __shfl_xor(m, 4));
    m = fmaxf(m, __shfl_xor(m, 8));
    float s = 0.f;
#pragma unroll
    for (int nt = 0; nt < 16; ++nt)
      if (nt < ntile) {
        vv[nt] = __expf(vv[nt] - m);
        s += vv[nt];
      }
    s += __shfl_xor(s, 1);
    s += __shfl_xor(s, 2);
    s += __shfl_xor(s, 4);
    s += __shfl_xor(s, 8);
    const float inv = 1.0f / s;
    const int sw = (prow & 7) << 3;
#pragma unroll
    for (int nt = 0; nt < 16; ++nt)
      if (nt < ntile) {
        const int col = nt * 16 + (l & 15);
        Pl[prow * 256 + (col ^ sw)] = f2bf(vv[nt] * inv);
      }
  }
  __syncthreads();
  f32x4 o[4][6] = {};
  const int nks = SKV >> 5;
  for (int ks = 0; ks < nks; ++ks) {
    const int kk = ks * 32 + (l >> 4) * 8;
    bf8 av[4];
#pragma unroll
    for (int mt = 0; mt < 4; ++mt) {
      const int rp = mt * 16 + (l & 15);
      av[mt] = *(const bf8*)&Pl[rp * 256 + (kk ^ ((rp & 7) << 3))];
    }
#pragma unroll
    for (int nt = 0; nt < 6; ++nt) {
      const int d = w * 96 + nt * 16 + (l & 15);
      bf8 bv = *(const bf8*)&vt[(size_t)b * (H_ * T_) + (size_t)d * T_ + kk];
#pragma unroll
      for (int mt = 0; mt < 4; ++mt)
        o[mt][nt] = __builtin_amdgcn_mfma_f32_16x16x32_bf16(av[mt], bv, o[mt][nt], 0, 0, 0);
    }
  }
#pragma unroll
  for (int mt = 0; mt < 4; ++mt) {
    const int tok = b * T_ + t0 + mt * 16 + (l >> 4) * 4;
#pragma unroll
    for (int nt = 0; nt < 6; ++nt) {
      const int d = w * 96 + nt * 16 + (l & 15);
#pragma unroll
      for (int r = 0; r < 4; ++r)
        out[(size_t)(tok + r) * H_ + d] = o[mt][nt][r];
    }
  }
}

// ---------------------------------------------------------------------------
extern "C" void kernel_launch(void* const* d_in, const int* in_sizes, int n_in,
                              void* d_out, int out_size, void* d_ws, size_t ws_size,
                              hipStream_t stream) {
  (void)in_sizes; (void)n_in; (void)out_size; (void)ws_size;
  const float* x = (const float*)d_in[0];
  const float* wk = (const float*)d_in[1];
  const float* wq = (const float*)d_in[2];
  const float* wv = (const float*)d_in[3];
  float* out = (float*)d_out;
  char* ws = (char*)d_ws;
  const size_t SZ = (size_t)B_ * T_ * H_ * 2;
  short* kbuf = (short*)ws;
  short* qbuf = (short*)(ws + SZ);
  short* vt   = (short*)(ws + 2 * SZ);
  short* xb = (short*)d_out;
  short* wb = (short*)((char*)d_out + SZ);
  convert_kernel<<<2048, 256, 0, stream>>>(x, wk, wq, wv, xb, wb);
  proj_gemm<<<1152, 512, 0, stream>>>(xb, wb, kbuf, qbuf, vt);
  attn_kernel<<<1024, 256, 0, stream>>>(qbuf, kbuf, vt, out);
}